// Round 5
// baseline (170.961 us; speedup 1.0000x reference)
//
#include <hip/hip_runtime.h>
#include <math.h>

// Problem constants (HeadAttention_738734374917)
#define Bn  8
#define Nn  2048
#define Dn  1024
#define DHn 64
#define PAD 72   // LDS row pitch (shorts): 144 B, 16B-aligned; b128 frag reads spread evenly

typedef __attribute__((ext_vector_type(8))) short bf16x8;  // 8 bf16 = 4 VGPRs
typedef __attribute__((ext_vector_type(4))) float f32x4;

static __device__ inline short f2bf(float f) {
    unsigned u = __builtin_bit_cast(unsigned, f);
    u += 0x7FFFu + ((u >> 16) & 1u);     // round-to-nearest-even
    return (short)(u >> 16);
}
static __device__ inline bf16x8 pack8(float4 a, float4 b) {
    bf16x8 v;
    v[0] = f2bf(a.x); v[1] = f2bf(a.y); v[2] = f2bf(a.z); v[3] = f2bf(a.w);
    v[4] = f2bf(b.x); v[5] = f2bf(b.y); v[6] = f2bf(b.z); v[7] = f2bf(b.w);
    return v;
}

// ---------------------------------------------------------------------------
// W transpose: Wt[col 0..191][k 0..1023] bf16, col = {Q|K|V} x 64.
// ---------------------------------------------------------------------------
__global__ __launch_bounds__(256) void wt_kernel(
    const float* __restrict__ Wq, const float* __restrict__ Wk,
    const float* __restrict__ Wv, short* __restrict__ Wt)
{
    const int gn = blockIdx.x;              // 0..191
    const float* Wm = (gn < 64) ? Wq : (gn < 128 ? Wk : Wv);
    const int n = gn & 63;
    const int t = threadIdx.x;
#pragma unroll
    for (int r = 0; r < 4; ++r) {
        const int k = t * 4 + r;
        Wt[gn * Dn + k] = f2bf(Wm[k * DHn + n]);
    }
}

// ---------------------------------------------------------------------------
// K1: QKV projection, bf16 MFMA.  Grid 512 (M=32 i-tiles, 2 blocks/CU), all
// 3 mats per block (x read ONCE), N=192 = 4 waves x 48.  W-frags direct from
// L2-resident Wt; xs double-buffered -> ONE barrier per kt.
// Outputs: Qb[i][d], Kb[j][d]*0.125, Vt[b][d][j] — all bf16.
// ---------------------------------------------------------------------------
__global__ __launch_bounds__(256) void qkv_kernel(
    const float* __restrict__ x, const short* __restrict__ Wt,
    const float* __restrict__ bq, const float* __restrict__ bk,
    const float* __restrict__ bv,
    short* __restrict__ Qb, short* __restrict__ Kb, short* __restrict__ Vt)
{
    __shared__ __attribute__((aligned(16))) short xs[2][32][PAD];

    const int t = threadIdx.x;
    const int w = t >> 6, lane = t & 63;
    const int c = lane & 15, quad = lane >> 4;
    const int ibase = blockIdx.x * 32;
    const int r0 = t >> 3, kc = t & 7;      // staging: row r0 (0..31), 8-elem chunk kc

    const float* xrow = &x[(size_t)(ibase + r0) * Dn + kc * 8];

    // stage kt=0 into buf 0
    {
        const float4 a = ((const float4*)xrow)[0];
        const float4 b = ((const float4*)xrow)[1];
        *(bf16x8*)&xs[0][r0][kc * 8] = pack8(a, b);
    }

    f32x4 acc[2][3];
#pragma unroll
    for (int mt = 0; mt < 2; ++mt)
#pragma unroll
        for (int nt = 0; nt < 3; ++nt) acc[mt][nt] = (f32x4){0.f, 0.f, 0.f, 0.f};

    __syncthreads();

    for (int kt = 0; kt < 16; ++kt) {
        const int cur = kt & 1;
        // W-frags for this kt (global, L2-resident, shared by all blocks)
        bf16x8 wf[2][3];
#pragma unroll
        for (int kk = 0; kk < 2; ++kk)
#pragma unroll
            for (int nt = 0; nt < 3; ++nt)
                wf[kk][nt] = *(const bf16x8*)&Wt[(size_t)(w * 48 + nt * 16 + c) * Dn
                                                 + kt * 64 + kk * 32 + quad * 8];
        // prefetch x for kt+1
        float4 pa, pb;
        if (kt < 15) {
            pa = ((const float4*)(xrow + (kt + 1) * 64))[0];
            pb = ((const float4*)(xrow + (kt + 1) * 64))[1];
        }
        // compute from buf cur
#pragma unroll
        for (int kk = 0; kk < 2; ++kk) {
            const bf16x8 af0 = *(const bf16x8*)&xs[cur][c][kk * 32 + quad * 8];
            const bf16x8 af1 = *(const bf16x8*)&xs[cur][16 + c][kk * 32 + quad * 8];
#pragma unroll
            for (int nt = 0; nt < 3; ++nt) {
                acc[0][nt] = __builtin_amdgcn_mfma_f32_16x16x32_bf16(af0, wf[kk][nt], acc[0][nt], 0, 0, 0);
                acc[1][nt] = __builtin_amdgcn_mfma_f32_16x16x32_bf16(af1, wf[kk][nt], acc[1][nt], 0, 0, 0);
            }
        }
        // stage kt+1 into the other buffer
        if (kt < 15) *(bf16x8*)&xs[1 - cur][r0][kc * 8] = pack8(pa, pb);
        __syncthreads();
    }

    // epilogue: bias, K-scale, store (mat uniform per (w,nt))
#pragma unroll
    for (int nt = 0; nt < 3; ++nt) {
        const int col = w * 48 + nt * 16 + c;
        const int mat = col >> 6, cm = col & 63;
        const float bias = (mat == 0 ? bq : (mat == 1 ? bk : bv))[cm];
#pragma unroll
        for (int mt = 0; mt < 2; ++mt) {
            if (mat == 2) {
                const int row = ibase + mt * 16 + quad * 4;
                const int b = row >> 11, i = row & (Nn - 1);
                ushort4 o;
                o.x = (unsigned short)f2bf(acc[mt][nt][0] + bias);
                o.y = (unsigned short)f2bf(acc[mt][nt][1] + bias);
                o.z = (unsigned short)f2bf(acc[mt][nt][2] + bias);
                o.w = (unsigned short)f2bf(acc[mt][nt][3] + bias);
                *(ushort4*)&Vt[((size_t)b * DHn + cm) * Nn + i] = o;
            } else {
                const float s = (mat == 1) ? 0.125f : 1.0f;
                short* Out = (mat == 0) ? Qb : Kb;
#pragma unroll
                for (int r = 0; r < 4; ++r)
                    Out[(size_t)(ibase + mt * 16 + quad * 4 + r) * DHn + cm] =
                        f2bf((acc[mt][nt][r] + bias) * s);
            }
        }
    }
}

// ---------------------------------------------------------------------------
// K2: l_part[s][b][j] = sum_{i in split s} exp(Q_i . K'_j).
// Grid = (b, j-tile 64, i-split 4) = 1024.  K-frags register-resident;
// Q double-buffered in LDS -> ONE barrier per 64-row chunk.  Plain stores.
// ---------------------------------------------------------------------------
__global__ __launch_bounds__(256) void colsum_kernel(
    const short* __restrict__ Qb, const short* __restrict__ Kb,
    float* __restrict__ lpart)
{
    __shared__ __attribute__((aligned(16))) short Qs[2][64][PAD];
    __shared__ float red[16][64];

    const int t = threadIdx.x;
    const int w = t >> 6, lane = t & 63;
    const int c = lane & 15, quad = lane >> 4;
    const int bid = blockIdx.x;
    const int b = bid >> 7, rem = bid & 127, jt = rem >> 2, s = rem & 3;
    const int jbase = jt * 64;
    const int r0 = t >> 2, cc = (t & 3) * 16;

    bf16x8 kb[4][2];
#pragma unroll
    for (int nt = 0; nt < 4; ++nt)
#pragma unroll
        for (int kk = 0; kk < 2; ++kk)
            kb[nt][kk] = *(const bf16x8*)&Kb[((size_t)b * Nn + jbase + nt * 16 + c) * DHn
                                             + kk * 32 + quad * 8];

    const short* qbase = &Qb[((size_t)b * Nn + s * 512 + r0) * DHn + cc];
    // stage it=0 into buf 0
    *(bf16x8*)&Qs[0][r0][cc]     = *(const bf16x8*)qbase;
    *(bf16x8*)&Qs[0][r0][cc + 8] = *(const bf16x8*)(qbase + 8);

    float lsum[4] = {0.f, 0.f, 0.f, 0.f};
    __syncthreads();

    for (int it = 0; it < 8; ++it) {
        const int cur = it & 1;
        bf16x8 p0, p1;
        if (it < 7) {
            const short* pq = qbase + (size_t)(it + 1) * 64 * DHn;
            p0 = *(const bf16x8*)pq; p1 = *(const bf16x8*)(pq + 8);
        }
        const bf16x8 aq0 = *(const bf16x8*)&Qs[cur][w * 16 + c][quad * 8];
        const bf16x8 aq1 = *(const bf16x8*)&Qs[cur][w * 16 + c][32 + quad * 8];
#pragma unroll
        for (int nt = 0; nt < 4; ++nt) {
            f32x4 sv = (f32x4){0.f, 0.f, 0.f, 0.f};
            sv = __builtin_amdgcn_mfma_f32_16x16x32_bf16(aq0, kb[nt][0], sv, 0, 0, 0);
            sv = __builtin_amdgcn_mfma_f32_16x16x32_bf16(aq1, kb[nt][1], sv, 0, 0, 0);
            lsum[nt] += __expf(sv[0]) + __expf(sv[1]) + __expf(sv[2]) + __expf(sv[3]);
        }
        if (it < 7) {
            *(bf16x8*)&Qs[1 - cur][r0][cc]     = p0;
            *(bf16x8*)&Qs[1 - cur][r0][cc + 8] = p1;
        }
        __syncthreads();
    }

#pragma unroll
    for (int nt = 0; nt < 4; ++nt) red[w * 4 + quad][nt * 16 + c] = lsum[nt];
    __syncthreads();
    if (t < 64) {
        float sum = 0.f;
#pragma unroll
        for (int r = 0; r < 16; ++r) sum += red[r][t];
        lpart[((size_t)s * Bn + b) * Nn + jbase + t] = sum;   // plain store
    }
}

// ---------------------------------------------------------------------------
// K3: outp[s][i,:] = sum_{j in s} (exp(Q_i.K'_j)/l_j) V[j,:].
// Grid = (b, i-tile 64, j-split 4) = 1024.  K/V double-buffered LDS staging
// (ONE barrier per tile); rl = 1/(sum of 4 l_parts) folded into P at exp;
// Ps wave-private C->A bounce; plain stores to per-split partials.
// ---------------------------------------------------------------------------
__global__ __launch_bounds__(256) void attnout_kernel(
    const short* __restrict__ Qb, const short* __restrict__ Kb,
    const short* __restrict__ Vt, const float* __restrict__ lpart,
    float* __restrict__ outp)
{
    __shared__ __attribute__((aligned(16))) short Ks[2][64][PAD];
    __shared__ __attribute__((aligned(16))) short Vs[2][64][PAD];
    __shared__ __attribute__((aligned(16))) short Ps[4][16][PAD];  // wave-private
    __shared__ float rls[2][64];

    const int t = threadIdx.x;
    const int w = t >> 6, lane = t & 63;
    const int c = lane & 15, quad = lane >> 4;
    const int bid = blockIdx.x;
    const int b = bid >> 7, rem = bid & 127, it = rem >> 2, s = rem & 3;
    const int ibase = it * 64;
    const int r0 = t >> 2, cc = (t & 3) * 16;

    const size_t qrow = (size_t)b * Nn + ibase + w * 16 + c;
    const bf16x8 aq0 = *(const bf16x8*)&Qb[qrow * DHn + quad * 8];
    const bf16x8 aq1 = *(const bf16x8*)&Qb[qrow * DHn + 32 + quad * 8];

    const short* kbase = &Kb[((size_t)b * Nn + s * 512 + r0) * DHn + cc];
    const short* vbase = &Vt[((size_t)b * DHn + r0) * Nn + s * 512 + cc];

    // stage tile 0 + rls[0]
    *(bf16x8*)&Ks[0][r0][cc]     = *(const bf16x8*)kbase;
    *(bf16x8*)&Ks[0][r0][cc + 8] = *(const bf16x8*)(kbase + 8);
    *(bf16x8*)&Vs[0][r0][cc]     = *(const bf16x8*)vbase;
    *(bf16x8*)&Vs[0][r0][cc + 8] = *(const bf16x8*)(vbase + 8);
    if (t < 64) {
        const size_t lj = (size_t)b * Nn + s * 512 + t;
        rls[0][t] = 1.0f / (lpart[lj] + lpart[(size_t)Bn * Nn + lj]
                          + lpart[2 * (size_t)Bn * Nn + lj] + lpart[3 * (size_t)Bn * Nn + lj]);
    }

    f32x4 acc[4];
#pragma unroll
    for (int dn = 0; dn < 4; ++dn) acc[dn] = (f32x4){0.f, 0.f, 0.f, 0.f};
    __syncthreads();

    for (int jt2 = 0; jt2 < 8; ++jt2) {
        const int cur = jt2 & 1;
        // prefetch next tile into registers
        bf16x8 pk0, pk1, pv0, pv1; float nrl;
        if (jt2 < 7) {
            const short* pk = kbase + (size_t)(jt2 + 1) * 64 * DHn;
            pk0 = *(const bf16x8*)pk; pk1 = *(const bf16x8*)(pk + 8);
            const short* pv = vbase + (jt2 + 1) * 64;
            pv0 = *(const bf16x8*)pv; pv1 = *(const bf16x8*)(pv + 8);
            if (t < 64) {
                const size_t lj = (size_t)b * Nn + s * 512 + (jt2 + 1) * 64 + t;
                nrl = 1.0f / (lpart[lj] + lpart[(size_t)Bn * Nn + lj]
                            + lpart[2 * (size_t)Bn * Nn + lj] + lpart[3 * (size_t)Bn * Nn + lj]);
            }
        }

        // S = Q.K'^T (16 i x 64 j per wave) -> P = exp(S)*rl -> Ps (A-layout)
#pragma unroll
        for (int nt = 0; nt < 4; ++nt) {
            const bf16x8 kb0 = *(const bf16x8*)&Ks[cur][nt * 16 + c][quad * 8];
            const bf16x8 kb1 = *(const bf16x8*)&Ks[cur][nt * 16 + c][32 + quad * 8];
            f32x4 sv = (f32x4){0.f, 0.f, 0.f, 0.f};
            sv = __builtin_amdgcn_mfma_f32_16x16x32_bf16(aq0, kb0, sv, 0, 0, 0);
            sv = __builtin_amdgcn_mfma_f32_16x16x32_bf16(aq1, kb1, sv, 0, 0, 0);
            const float rl = rls[cur][nt * 16 + c];
#pragma unroll
            for (int r = 0; r < 4; ++r)
                Ps[w][quad * 4 + r][nt * 16 + c] = f2bf(__expf(sv[r]) * rl);
        }
        // wave-private: same-wave DS ops are in-order, no block barrier
        const bf16x8 ap0 = *(const bf16x8*)&Ps[w][c][quad * 8];
        const bf16x8 ap1 = *(const bf16x8*)&Ps[w][c][32 + quad * 8];
#pragma unroll
        for (int dn = 0; dn < 4; ++dn) {
            const bf16x8 vb0 = *(const bf16x8*)&Vs[cur][dn * 16 + c][quad * 8];
            const bf16x8 vb1 = *(const bf16x8*)&Vs[cur][dn * 16 + c][32 + quad * 8];
            acc[dn] = __builtin_amdgcn_mfma_f32_16x16x32_bf16(ap0, vb0, acc[dn], 0, 0, 0);
            acc[dn] = __builtin_amdgcn_mfma_f32_16x16x32_bf16(ap1, vb1, acc[dn], 0, 0, 0);
        }

        if (jt2 < 7) {
            *(bf16x8*)&Ks[1 - cur][r0][cc]     = pk0;
            *(bf16x8*)&Ks[1 - cur][r0][cc + 8] = pk1;
            *(bf16x8*)&Vs[1 - cur][r0][cc]     = pv0;
            *(bf16x8*)&Vs[1 - cur][r0][cc + 8] = pv1;
            if (t < 64) rls[1 - cur][t] = nrl;
        }
        __syncthreads();
    }

    float* op = outp + (size_t)s * (Bn * Nn * DHn) + ((size_t)b * Nn + ibase) * DHn;
#pragma unroll
    for (int dn = 0; dn < 4; ++dn)
#pragma unroll
        for (int r = 0; r < 4; ++r)
            op[(w * 16 + quad * 4 + r) * DHn + dn * 16 + c] = acc[dn][r];
}

// ---------------------------------------------------------------------------
// Reduce the 4 partial buffers into out.
// ---------------------------------------------------------------------------
__global__ __launch_bounds__(256) void outreduce_kernel(
    const float* __restrict__ outp, float* __restrict__ out)
{
    const int id = blockIdx.x * 256 + threadIdx.x;   // 262144 float4
    const float4* p = (const float4*)outp;
    const float4 a = p[id];
    const float4 b = p[id + 262144];
    const float4 c = p[id + 2 * 262144];
    const float4 d = p[id + 3 * 262144];
    float4 r;
    r.x = a.x + b.x + c.x + d.x;
    r.y = a.y + b.y + c.y + d.y;
    r.z = a.z + b.z + c.z + d.z;
    r.w = a.w + b.w + c.w + d.w;
    ((float4*)out)[id] = r;
}

// ---------------------------------------------------------------------------
extern "C" void kernel_launch(void* const* d_in, const int* in_sizes, int n_in,
                              void* d_out, int out_size, void* d_ws, size_t ws_size,
                              hipStream_t stream)
{
    const float* x  = (const float*)d_in[0];
    const float* Wq = (const float*)d_in[1];
    const float* bq = (const float*)d_in[2];
    const float* Wk = (const float*)d_in[3];
    const float* bk = (const float*)d_in[4];
    const float* Wv = (const float*)d_in[5];
    const float* bv = (const float*)d_in[6];
    float* out = (float*)d_out;

    char* ws = (char*)d_ws;
    short* Qb    = (short*)(ws);                                   // 2 MB
    short* Kb    = (short*)(ws + (size_t)(1 << 21));               // 2 MB
    short* Vt    = (short*)(ws + (size_t)(2 << 21));               // 2 MB [b][d][j]
    short* Wt    = (short*)(ws + (size_t)(3 << 21));               // 384 KB
    float* lpart = (float*)(ws + (size_t)(3 << 21) + (1 << 19));   // 256 KB (4 splits)
    float* outp  = (float*)(ws + (size_t)(7 << 20));               // 16 MB (4 partials)

    wt_kernel<<<dim3(192), dim3(256), 0, stream>>>(Wq, Wk, Wv, Wt);
    qkv_kernel<<<dim3(512), dim3(256), 0, stream>>>(x, Wt, bq, bk, bv, Qb, Kb, Vt);
    colsum_kernel<<<dim3(1024), dim3(256), 0, stream>>>(Qb, Kb, lpart);
    attnout_kernel<<<dim3(1024), dim3(256), 0, stream>>>(Qb, Kb, Vt, lpart, outp);
    outreduce_kernel<<<dim3(1024), dim3(256), 0, stream>>>(outp, out);
}